// Round 1
// baseline (119.618 us; speedup 1.0000x reference)
//
#include <hip/hip_runtime.h>

#define IN_CH 64
#define OUT_CH 128
#define HW 128
#define KTAPS 9
#define ICP 72  // padded ic pitch (elements) -> 144 B row, 16B-aligned

typedef __bf16 bf16x8 __attribute__((ext_vector_type(8)));
typedef float f32x16 __attribute__((ext_vector_type(16)));

// fp32 -> bf16 round-to-nearest-even (data has no NaN/Inf)
__device__ __forceinline__ unsigned short f2bf(float f) {
    unsigned u = __builtin_bit_cast(unsigned, f);
    unsigned r = (u + 0x7FFFu + ((u >> 16) & 1u)) >> 16;
    return (unsigned short)r;
}

// W (OIHW fp32, 128x64x3x3) -> Wl bf16 [oc][tap][ic], tap = kh*3+kw
__global__ void wprep_kernel(const float* __restrict__ W, unsigned short* __restrict__ Wl) {
    int i = blockIdx.x * blockDim.x + threadIdx.x;
    if (i >= OUT_CH * IN_CH * KTAPS) return;
    int oc  = i / (IN_CH * KTAPS);
    int r   = i % (IN_CH * KTAPS);
    int tap = r >> 6;   // 0..8
    int ic  = r & 63;
    int kh = tap / 3, kw = tap % 3;
    Wl[i] = f2bf(W[((oc * IN_CH + ic) * 3 + kh) * 3 + kw]);
}

__global__ __launch_bounds__(256, 2) void conv_kernel(
    const float* __restrict__ x, const unsigned short* __restrict__ Wl,
    const float* __restrict__ bias, float* __restrict__ y)
{
    __shared__ __align__(16) unsigned short xs[3 * HW * ICP];  // 55296 B

    int bid = blockIdx.x;
    int sb  = (bid & 7) * 256 + (bid >> 3);   // XCD-contiguous h ranges
    int n = sb >> 7, h = sb & 127;
    int tid = threadIdx.x;

    // ---- stage x rows (h-8, h, h+8) as bf16 into xs[kh][w][ic] ----
    {
        int w = tid & 127;
        for (int s = tid >> 7; s < 48; s += 2) {   // 48 slabs: (kh, ic-group-of-4)
            int kh  = s >> 4;
            int ic4 = (s & 15) << 2;
            int srow = (h + kh * 8 + 120) & 127;   // h-8, h, h+8 (mod 128)
            const float* xp = x + (((n * IN_CH + ic4) * HW + srow) * HW + w);
            unsigned u0 = (unsigned)f2bf(xp[0]);
            unsigned u1 = (unsigned)f2bf(xp[16384]);   // +1 ic
            unsigned u2 = (unsigned)f2bf(xp[32768]);
            unsigned u3 = (unsigned)f2bf(xp[49152]);
            uint2 pk;
            pk.x = u0 | (u1 << 16);
            pk.y = u2 | (u3 << 16);
            *reinterpret_cast<uint2*>(&xs[(kh * HW + w) * ICP + ic4]) = pk;
        }
    }
    __syncthreads();

    // ---- implicit GEMM: Y[128 oc][128 w] = Wl[128][576] * X[576][128] ----
    int wid  = tid >> 6;
    int lane = tid & 63;
    int wr = wid >> 1, wc = wid & 1;    // wave's oc-half / w-half
    int l31 = lane & 31, lhi = lane >> 5;

    f32x16 acc[2][2];
    #pragma unroll
    for (int a = 0; a < 2; ++a)
        #pragma unroll
        for (int bq = 0; bq < 2; ++bq)
            #pragma unroll
            for (int r = 0; r < 16; ++r) acc[a][bq][r] = 0.0f;

    // A-frag bases: row oc = wr*64 + mi*32 + l31 ; per-lane k offset lhi*8
    const unsigned short* A0 = Wl + (wr * 64 + l31) * (IN_CH * KTAPS) + lhi * 8;
    const unsigned short* A1 = A0 + 32 * (IN_CH * KTAPS);

    #pragma unroll 1
    for (int kh = 0; kh < 3; ++kh) {
        #pragma unroll
        for (int kw = 0; kw < 3; ++kw) {
            int tap = kh * 3 + kw;
            int xc0 = (wc * 64 + l31 + 8 * kw - 8) & 127;        // ni=0 column (circular)
            int xc1 = (wc * 64 + 32 + l31 + 8 * kw - 8) & 127;   // ni=1 column
            const unsigned short* B0 = &xs[(kh * HW + xc0) * ICP + lhi * 8];
            const unsigned short* B1 = &xs[(kh * HW + xc1) * ICP + lhi * 8];
            const unsigned short* At = A0 + tap * 64;
            const unsigned short* Au = A1 + tap * 64;
            #pragma unroll
            for (int ks = 0; ks < 4; ++ks) {   // K=16 per MFMA, 64 ic per tap
                bf16x8 a0 = *reinterpret_cast<const bf16x8*>(At + ks * 16);
                bf16x8 a1 = *reinterpret_cast<const bf16x8*>(Au + ks * 16);
                bf16x8 b0 = *reinterpret_cast<const bf16x8*>(B0 + ks * 16);
                bf16x8 b1 = *reinterpret_cast<const bf16x8*>(B1 + ks * 16);
                acc[0][0] = __builtin_amdgcn_mfma_f32_32x32x16_bf16(a0, b0, acc[0][0], 0, 0, 0);
                acc[0][1] = __builtin_amdgcn_mfma_f32_32x32x16_bf16(a0, b1, acc[0][1], 0, 0, 0);
                acc[1][0] = __builtin_amdgcn_mfma_f32_32x32x16_bf16(a1, b0, acc[1][0], 0, 0, 0);
                acc[1][1] = __builtin_amdgcn_mfma_f32_32x32x16_bf16(a1, b1, acc[1][1], 0, 0, 0);
            }
        }
    }

    // ---- epilogue: bias + store. D: col=l31(w), row=(reg&3)+8*(reg>>2)+4*lhi ----
    int outbase = (n * OUT_CH) * HW * HW + h * HW;
    #pragma unroll
    for (int mi = 0; mi < 2; ++mi) {
        #pragma unroll
        for (int ni = 0; ni < 2; ++ni) {
            int wcol = wc * 64 + ni * 32 + l31;
            #pragma unroll
            for (int reg = 0; reg < 16; ++reg) {
                int oc = wr * 64 + mi * 32 + (reg & 3) + 8 * (reg >> 2) + 4 * lhi;
                y[outbase + oc * HW * HW + wcol] = acc[mi][ni][reg] + bias[oc];
            }
        }
    }
}

extern "C" void kernel_launch(void* const* d_in, const int* in_sizes, int n_in,
                              void* d_out, int out_size, void* d_ws, size_t ws_size,
                              hipStream_t stream) {
    const float* x = (const float*)d_in[0];
    const float* W = (const float*)d_in[1];
    const float* b = (const float*)d_in[2];
    float* y = (float*)d_out;
    unsigned short* Wl = (unsigned short*)d_ws;  // 147456 B

    hipLaunchKernelGGL(wprep_kernel, dim3((OUT_CH * IN_CH * KTAPS + 255) / 256), dim3(256), 0, stream, W, Wl);
    hipLaunchKernelGGL(conv_kernel, dim3(16 * HW), dim3(256), 0, stream, x, Wl, b, y);
}

// Round 2
// 105.280 us; speedup vs baseline: 1.1362x; 1.1362x over previous
//
#include <hip/hip_runtime.h>

#define IN_CH 64
#define OUT_CH 128
#define HW 128
#define KTAPS 9

typedef __bf16 bf16x8 __attribute__((ext_vector_type(8)));
typedef float f32x16 __attribute__((ext_vector_type(16)));
typedef float f32x4 __attribute__((ext_vector_type(4)));

// fp32 -> bf16 round-to-nearest-even (data has no NaN/Inf, |x| << bf16 max)
__device__ __forceinline__ unsigned f2bf(float f) {
    unsigned u = __builtin_bit_cast(unsigned, f);
    return (u + 0x7FFFu + ((u >> 16) & 1u)) >> 16;
}

// 3-bit row hash -> XOR on byte-addr bits 4..6 (16B granules within a 128B row).
// Spreads both ds_write_b128 (staging) and ds_read_b128 (B-frags) to the
// BW-optimal 4-way bank pattern without padding (keeps LDS at 48KB -> 3 blocks/CU).
__device__ __forceinline__ int swz(int row) { return ((row ^ (row >> 3)) & 7) << 4; }

// W (OIHW fp32, 128x64x3x3) -> Wl bf16 [oc][tap][ic], tap = kh*3+kw
__global__ void wprep_kernel(const float* __restrict__ W, unsigned short* __restrict__ Wl) {
    int i = blockIdx.x * blockDim.x + threadIdx.x;
    if (i >= OUT_CH * IN_CH * KTAPS) return;
    int oc  = i / (IN_CH * KTAPS);
    int r   = i % (IN_CH * KTAPS);
    int tap = r >> 6;   // 0..8
    int ic  = r & 63;
    int kh = tap / 3, kw = tap % 3;
    Wl[i] = (unsigned short)f2bf(W[((oc * IN_CH + ic) * 3 + kh) * 3 + kw]);
}

__global__ __launch_bounds__(256, 3) void conv_kernel(
    const float* __restrict__ x, const unsigned short* __restrict__ Wl,
    const float* __restrict__ bias, float* __restrict__ y)
{
    // xs layout: row = kh*128 + w (0..383), each row = 64 ic bf16 = 128B,
    // byte addr = row*128 + ic*2, then XOR-swizzled within the row.
    __shared__ __align__(16) unsigned char xs[3 * HW * 128];  // 49152 B

    int bid = blockIdx.x;
    int sb  = (bid & 7) * 256 + (bid >> 3);   // XCD-contiguous h ranges
    int n = sb >> 7, h = sb & 127;
    int tid = threadIdx.x;

    // ---- stage x rows (h-8, h, h+8) as bf16 into xs[kh][w][ic] ----
    // 768 groups: (kh, ic8, w4). Per group: 8x float4 (w-contig, coalesced),
    // pack 8 ic into uint4, 4x ds_write_b128 (swizzled).
    #pragma unroll
    for (int it = 0; it < 3; ++it) {
        int q   = it * 256 + tid;    // 0..767
        int w4  = q & 31;
        int ic8 = (q >> 5) & 7;
        int kh  = q >> 8;            // 0..2
        int srow = (h + kh * 8 + 120) & 127;   // h-8, h, h+8 (mod 128)
        const float* xp = x + (((n * IN_CH + ic8 * 8) * HW + srow) * HW + w4 * 4);
        f32x4 v[8];
        #pragma unroll
        for (int j = 0; j < 8; ++j)
            v[j] = *reinterpret_cast<const f32x4*>(xp + j * (HW * HW));
        #pragma unroll
        for (int j2 = 0; j2 < 4; ++j2) {
            int row = kh * HW + w4 * 4 + j2;
            uint4 pk;
            pk.x = f2bf(v[0][j2]) | (f2bf(v[1][j2]) << 16);
            pk.y = f2bf(v[2][j2]) | (f2bf(v[3][j2]) << 16);
            pk.z = f2bf(v[4][j2]) | (f2bf(v[5][j2]) << 16);
            pk.w = f2bf(v[6][j2]) | (f2bf(v[7][j2]) << 16);
            int addr = (row * 128 + ic8 * 16) ^ swz(row);
            *reinterpret_cast<uint4*>(xs + addr) = pk;
        }
    }
    __syncthreads();

    // ---- implicit GEMM: Y[128 oc][128 w] = Wl[128][576] * X[576][128] ----
    int wid  = tid >> 6;
    int lane = tid & 63;
    int wr = wid >> 1, wc = wid & 1;    // wave's oc-half / w-half
    int l31 = lane & 31, lhi = lane >> 5;

    f32x16 acc[2][2];
    #pragma unroll
    for (int a = 0; a < 2; ++a)
        #pragma unroll
        for (int bq = 0; bq < 2; ++bq)
            #pragma unroll
            for (int r = 0; r < 16; ++r) acc[a][bq][r] = 0.0f;

    // A-frag bases: row oc = wr*64 + mi*32 + l31 ; per-lane k offset lhi*8
    const unsigned short* A0 = Wl + (wr * 64 + l31) * (IN_CH * KTAPS) + lhi * 8;
    const unsigned short* A1 = A0 + 32 * (IN_CH * KTAPS);

    #pragma unroll 1
    for (int kh = 0; kh < 3; ++kh) {
        #pragma unroll
        for (int kw = 0; kw < 3; ++kw) {
            int tap = kh * 3 + kw;
            int xc0 = (wc * 64 + l31 + 8 * kw - 8) & 127;   // circular column
            int xc1 = (xc0 + 32) & 127;
            int r0 = kh * HW + xc0;
            int r1 = kh * HW + xc1;
            int b0base = r0 * 128 + lhi * 16, s0 = swz(r0);
            int b1base = r1 * 128 + lhi * 16, s1 = swz(r1);
            const unsigned short* At = A0 + tap * 64;
            const unsigned short* Au = A1 + tap * 64;
            #pragma unroll
            for (int ks = 0; ks < 4; ++ks) {   // K=16 per MFMA, 64 ic per tap
                bf16x8 a0 = *reinterpret_cast<const bf16x8*>(At + ks * 16);
                bf16x8 a1 = *reinterpret_cast<const bf16x8*>(Au + ks * 16);
                bf16x8 b0 = *reinterpret_cast<const bf16x8*>(xs + ((b0base + ks * 32) ^ s0));
                bf16x8 b1 = *reinterpret_cast<const bf16x8*>(xs + ((b1base + ks * 32) ^ s1));
                acc[0][0] = __builtin_amdgcn_mfma_f32_32x32x16_bf16(a0, b0, acc[0][0], 0, 0, 0);
                acc[0][1] = __builtin_amdgcn_mfma_f32_32x32x16_bf16(a0, b1, acc[0][1], 0, 0, 0);
                acc[1][0] = __builtin_amdgcn_mfma_f32_32x32x16_bf16(a1, b0, acc[1][0], 0, 0, 0);
                acc[1][1] = __builtin_amdgcn_mfma_f32_32x32x16_bf16(a1, b1, acc[1][1], 0, 0, 0);
            }
        }
    }

    // ---- epilogue: bias + store. D: col=l31(w), row=(reg&3)+8*(reg>>2)+4*lhi ----
    int outbase = (n * OUT_CH) * HW * HW + h * HW;
    #pragma unroll
    for (int mi = 0; mi < 2; ++mi) {
        #pragma unroll
        for (int ni = 0; ni < 2; ++ni) {
            int wcol = wc * 64 + ni * 32 + l31;
            #pragma unroll
            for (int reg = 0; reg < 16; ++reg) {
                int oc = wr * 64 + mi * 32 + (reg & 3) + 8 * (reg >> 2) + 4 * lhi;
                y[outbase + oc * HW * HW + wcol] = acc[mi][ni][reg] + bias[oc];
            }
        }
    }
}

extern "C" void kernel_launch(void* const* d_in, const int* in_sizes, int n_in,
                              void* d_out, int out_size, void* d_ws, size_t ws_size,
                              hipStream_t stream) {
    const float* x = (const float*)d_in[0];
    const float* W = (const float*)d_in[1];
    const float* b = (const float*)d_in[2];
    float* y = (float*)d_out;
    unsigned short* Wl = (unsigned short*)d_ws;  // 147456 B

    hipLaunchKernelGGL(wprep_kernel, dim3((OUT_CH * IN_CH * KTAPS + 255) / 256), dim3(256), 0, stream, W, Wl);
    hipLaunchKernelGGL(conv_kernel, dim3(16 * HW), dim3(256), 0, stream, x, Wl, b, y);
}